// Round 2
// baseline (205.827 us; speedup 1.0000x reference)
//
#include <hip/hip_runtime.h>
#include <hip/hip_bf16.h>
#include <math.h>

// Problem constants
#define N 2048
#define NFEAT 128
#define NHID 32
#define NCLASS 16

// ws layout (float elements)
#define WS_T1    0                         // [2048][32]
#define WS_Y0    65536                     // [2048][16]
#define WS_WA    98304                     // [32]
#define WS_WB    98336                     // [32]
#define WS_CB    98368                     // [1]
#define WS_PART2 98432                     // [4][2048][32]
#define WS_Y     360576                    // [2048][16]
#define WS_PC    393344                    // [2048]
#define WS_Q     395392                    // [2048]
#define WS_PART3 397440                    // [4][2048][16]
// total 528512 floats = 2.02 MB

// ---------------------------------------------------------------------------
// K1: t1 = x_init @ W1 ; y0 = x_init @ W2[32:160] ; block0 computes wa,wb,cb
// ---------------------------------------------------------------------------
__global__ __launch_bounds__(256) void k1_prep(
    const float* __restrict__ x_init, const float* __restrict__ W1,
    const float* __restrict__ W2, const float* __restrict__ Wc1,
    const float* __restrict__ bc1, const float* __restrict__ Wc2,
    const float* __restrict__ bc2, float* __restrict__ ws)
{
    __shared__ float xs[8 * 128];
    __shared__ float W1s[128 * 32];
    __shared__ float W2bs[128 * 16];
    int t = threadIdx.x;
    int blk = blockIdx.x;

    for (int i = t; i < 1024; i += 256) xs[i] = x_init[blk * 1024 + i];
    for (int i = t; i < 4096; i += 256) W1s[i] = W1[i];
    for (int i = t; i < 2048; i += 256) W2bs[i] = W2[512 + i];  // rows 32..159
    __syncthreads();

    int rl = t >> 5, c = t & 31;
    int r = blk * 8 + rl;

    float acc = 0.f;
    #pragma unroll 8
    for (int k = 0; k < 128; ++k) acc = fmaf(xs[rl * 128 + k], W1s[k * 32 + c], acc);
    ws[WS_T1 + r * 32 + c] = acc;

    if (c < 16) {
        float a2 = 0.f;
        #pragma unroll 8
        for (int k = 0; k < 128; ++k) a2 = fmaf(xs[rl * 128 + k], W2bs[k * 16 + c], a2);
        ws[WS_Y0 + r * 16 + c] = a2;
    }

    if (blk == 0 && t < 32) {
        float wa = 0.f, wb = 0.f;
        for (int h = 0; h < 32; ++h) {
            float w = Wc2[h];
            wa = fmaf(Wc1[t * 32 + h], w, wa);
            wb = fmaf(Wc1[(32 + t) * 32 + h], w, wb);
        }
        ws[WS_WA + t] = wa;
        ws[WS_WB + t] = wb;
        if (t == 0) {
            float cb = bc2[0];
            for (int h = 0; h < 32; ++h) cb = fmaf(bc1[h], Wc2[h], cb);
            ws[WS_CB] = cb;
        }
    }
}

// ---------------------------------------------------------------------------
// K2: partial2[ks][r][c] = sum_{j in ks-strip} adj[r,j] * t1[j,c]
// wave = 8 rows x 8 jgroups; 4 waves/block; 256 blocks -> 1024 waves
// ---------------------------------------------------------------------------
__global__ __launch_bounds__(256) void k2_mm(
    const float* __restrict__ A, const float* __restrict__ ws_in,
    float* __restrict__ ws_out)
{
    const float* t1 = ws_in + WS_T1;
    int t = threadIdx.x;
    int wv = t >> 6;
    int lane = t & 63;
    int w = blockIdx.x * 4 + wv;       // 0..1023
    int rg = w >> 2;                   // 0..255
    int ks = w & 3;                    // 0..3
    int jg = lane & 7;
    int rl = lane >> 3;
    int r = rg * 8 + rl;
    int jbase = ks * 512;

    const float* Arow = A + (size_t)r * N + jbase + jg * 4;

    float acc[32];
    #pragma unroll
    for (int c = 0; c < 32; ++c) acc[c] = 0.f;

    for (int it = 0; it < 16; ++it) {
        float4 a4 = *reinterpret_cast<const float4*>(Arow + it * 32);
        const float* trow = t1 + (jbase + it * 32 + jg * 4) * 32;
        #pragma unroll
        for (int jj = 0; jj < 4; ++jj) {
            float av = (jj == 0) ? a4.x : (jj == 1) ? a4.y : (jj == 2) ? a4.z : a4.w;
            const float* tr = trow + jj * 32;
            #pragma unroll
            for (int q8 = 0; q8 < 8; ++q8) {
                float4 tv = *reinterpret_cast<const float4*>(tr + q8 * 4);
                acc[q8 * 4 + 0] = fmaf(av, tv.x, acc[q8 * 4 + 0]);
                acc[q8 * 4 + 1] = fmaf(av, tv.y, acc[q8 * 4 + 1]);
                acc[q8 * 4 + 2] = fmaf(av, tv.z, acc[q8 * 4 + 2]);
                acc[q8 * 4 + 3] = fmaf(av, tv.w, acc[q8 * 4 + 3]);
            }
        }
    }

    // butterfly reduce across the 8 jgroups (lane bits 0..2)
    #pragma unroll
    for (int d = 1; d < 8; d <<= 1) {
        #pragma unroll
        for (int c = 0; c < 32; ++c) acc[c] += __shfl_xor(acc[c], d);
    }

    // every lane now has the full row sum; lane jg writes its float4 slice
    float4 o;
    o.x = acc[jg * 4 + 0]; o.y = acc[jg * 4 + 1];
    o.z = acc[jg * 4 + 2]; o.w = acc[jg * 4 + 3];
    *reinterpret_cast<float4*>(ws_out + WS_PART2 + ((size_t)(ks * N + r)) * 32 + jg * 4) = o;
}

// ---------------------------------------------------------------------------
// K2b: x = tanh(sum partials + b1); p,q row scalars; y = x@W2[:32] + y0
// block 256 = 8 rows x 32 lanes
// ---------------------------------------------------------------------------
__global__ __launch_bounds__(256) void k2b_post(
    const float* __restrict__ b1, const float* __restrict__ W2,
    float* __restrict__ ws)
{
    __shared__ float xs[8][32];
    int t = threadIdx.x;
    int rl = t >> 5, c = t & 31;
    int r = blockIdx.x * 8 + rl;

    const float* p2 = ws + WS_PART2;
    float s = p2[(size_t)r * 32 + c]
            + p2[(size_t)(N + r) * 32 + c]
            + p2[(size_t)(2 * N + r) * 32 + c]
            + p2[(size_t)(3 * N + r) * 32 + c]
            + b1[c];
    float x = tanhf(s);
    xs[rl][c] = x;
    __syncthreads();

    float pp = x * ws[WS_WA + c];
    float qq = x * ws[WS_WB + c];
    #pragma unroll
    for (int d = 1; d < 32; d <<= 1) {
        pp += __shfl_xor(pp, d);
        qq += __shfl_xor(qq, d);
    }
    if (c == 0) {
        ws[WS_PC + r] = pp + ws[WS_CB];
        ws[WS_Q + r] = qq;
    }

    if (c < 16) {
        float acc = ws[WS_Y0 + r * 16 + c];
        #pragma unroll 8
        for (int h = 0; h < 32; ++h) acc = fmaf(xs[rl][h], W2[h * 16 + c], acc);
        ws[WS_Y + r * 16 + c] = acc;
    }
}

// ---------------------------------------------------------------------------
// K3: partial3[ks][r][c16] = sum_{j in strip} adj[r,j]*score(pc[r]+q[j])*y[j,c16]
// ---------------------------------------------------------------------------
__global__ __launch_bounds__(256) void k3_mm(
    const float* __restrict__ A, const float* __restrict__ ws_in,
    float* __restrict__ ws_out)
{
    const float* y = ws_in + WS_Y;
    const float* qv = ws_in + WS_Q;
    int t = threadIdx.x;
    int wv = t >> 6;
    int lane = t & 63;
    int w = blockIdx.x * 4 + wv;
    int rg = w >> 2;
    int ks = w & 3;
    int jg = lane & 7;
    int rl = lane >> 3;
    int r = rg * 8 + rl;
    int jbase = ks * 512;

    float pcr = ws_in[WS_PC + r];
    const float* Arow = A + (size_t)r * N + jbase + jg * 4;

    float acc[16];
    #pragma unroll
    for (int c = 0; c < 16; ++c) acc[c] = 0.f;

    for (int it = 0; it < 16; ++it) {
        float4 a4 = *reinterpret_cast<const float4*>(Arow + it * 32);
        int j0 = jbase + it * 32 + jg * 4;
        float4 q4 = *reinterpret_cast<const float4*>(qv + j0);
        #pragma unroll
        for (int jj = 0; jj < 4; ++jj) {
            float av = (jj == 0) ? a4.x : (jj == 1) ? a4.y : (jj == 2) ? a4.z : a4.w;
            float qj = (jj == 0) ? q4.x : (jj == 1) ? q4.y : (jj == 2) ? q4.z : q4.w;
            float e = pcr + qj;
            float sc = (e > 0.f) ? 1.f : e;
            float coef = av * sc;
            const float* yr = y + (j0 + jj) * 16;
            #pragma unroll
            for (int q8 = 0; q8 < 4; ++q8) {
                float4 tv = *reinterpret_cast<const float4*>(yr + q8 * 4);
                acc[q8 * 4 + 0] = fmaf(coef, tv.x, acc[q8 * 4 + 0]);
                acc[q8 * 4 + 1] = fmaf(coef, tv.y, acc[q8 * 4 + 1]);
                acc[q8 * 4 + 2] = fmaf(coef, tv.z, acc[q8 * 4 + 2]);
                acc[q8 * 4 + 3] = fmaf(coef, tv.w, acc[q8 * 4 + 3]);
            }
        }
    }

    #pragma unroll
    for (int d = 1; d < 8; d <<= 1) {
        #pragma unroll
        for (int c = 0; c < 16; ++c) acc[c] += __shfl_xor(acc[c], d);
    }

    float2 o;
    o.x = acc[jg * 2 + 0];
    o.y = acc[jg * 2 + 1];
    *reinterpret_cast<float2*>(ws_out + WS_PART3 + ((size_t)(ks * N + r)) * 16 + jg * 2) = o;
}

// ---------------------------------------------------------------------------
// K3b: out[r] = log_softmax(sum partials + b2)
// block 256 = 16 rows x 16 lanes
// ---------------------------------------------------------------------------
__global__ __launch_bounds__(256) void k3b_lsm(
    const float* __restrict__ b2, const float* __restrict__ ws,
    float* __restrict__ out)
{
    int t = threadIdx.x;
    int rl = t >> 4, c = t & 15;
    int r = blockIdx.x * 16 + rl;

    const float* p3 = ws + WS_PART3;
    float o = p3[(size_t)r * 16 + c]
            + p3[(size_t)(N + r) * 16 + c]
            + p3[(size_t)(2 * N + r) * 16 + c]
            + p3[(size_t)(3 * N + r) * 16 + c]
            + b2[c];

    float m = o;
    #pragma unroll
    for (int d = 1; d < 16; d <<= 1) m = fmaxf(m, __shfl_xor(m, d));
    float ex = expf(o - m);
    float sm = ex;
    #pragma unroll
    for (int d = 1; d < 16; d <<= 1) sm += __shfl_xor(sm, d);

    out[r * 16 + c] = o - m - logf(sm);
}

// ---------------------------------------------------------------------------
extern "C" void kernel_launch(void* const* d_in, const int* in_sizes, int n_in,
                              void* d_out, int out_size, void* d_ws, size_t ws_size,
                              hipStream_t stream)
{
    const float* x_init = (const float*)d_in[0];
    // d_in[1] adj: unused by the reference
    const float* adj1   = (const float*)d_in[2];
    // d_in[3] fully_connected_graph: unused
    const float* W1  = (const float*)d_in[4];
    const float* b1  = (const float*)d_in[5];
    const float* W2  = (const float*)d_in[6];
    const float* b2  = (const float*)d_in[7];
    const float* Wc1 = (const float*)d_in[8];
    const float* bc1 = (const float*)d_in[9];
    const float* Wc2 = (const float*)d_in[10];
    const float* bc2 = (const float*)d_in[11];
    float* out = (float*)d_out;
    float* ws = (float*)d_ws;

    hipLaunchKernelGGL(k1_prep, dim3(256), dim3(256), 0, stream,
                       x_init, W1, W2, Wc1, bc1, Wc2, bc2, ws);
    hipLaunchKernelGGL(k2_mm, dim3(256), dim3(256), 0, stream, adj1, ws, ws);
    hipLaunchKernelGGL(k2b_post, dim3(256), dim3(256), 0, stream, b1, W2, ws);
    hipLaunchKernelGGL(k3_mm, dim3(256), dim3(256), 0, stream, adj1, ws, ws);
    hipLaunchKernelGGL(k3b_lsm, dim3(128), dim3(256), 0, stream, b2, ws, out);
}

// Round 3
// 203.024 us; speedup vs baseline: 1.0138x; 1.0138x over previous
//
#include <hip/hip_runtime.h>
#include <hip/hip_bf16.h>
#include <math.h>

// Problem constants
#define N 2048
#define NFEAT 128
#define NHID 32
#define NCLASS 16
#define NSTRIP 16          // K-split factor for the two N x N GEMMs
#define KS 128             // strip width = N / NSTRIP

// ws layout (float elements)
#define WS_T1    0                         // [2048][32]
#define WS_Y0    65536                     // [2048][16]
#define WS_WA    98304                     // [32]
#define WS_WB    98336                     // [32]
#define WS_CB    98368                     // [1] (+pad)
#define WS_PART2 98432                     // [16][2048][32]
#define WS_Y     1147008                   // [2048][16]
#define WS_PC    1179776                   // [2048]
#define WS_Q     1181824                   // [2048]
#define WS_PART3 1183872                   // [16][2048][16]
// total 1708160 floats = 6.83 MB

// ---------------------------------------------------------------------------
// K1: t1 = x_init @ W1 ; y0 = x_init @ W2[32:160] ; block0 computes wa,wb,cb
// ---------------------------------------------------------------------------
__global__ __launch_bounds__(256) void k1_prep(
    const float* __restrict__ x_init, const float* __restrict__ W1,
    const float* __restrict__ W2, const float* __restrict__ Wc1,
    const float* __restrict__ bc1, const float* __restrict__ Wc2,
    const float* __restrict__ bc2, float* __restrict__ ws)
{
    __shared__ float xs[8 * 128];
    __shared__ float W1s[128 * 32];
    __shared__ float W2bs[128 * 16];
    int t = threadIdx.x;
    int blk = blockIdx.x;

    for (int i = t; i < 1024; i += 256) xs[i] = x_init[blk * 1024 + i];
    for (int i = t; i < 4096; i += 256) W1s[i] = W1[i];
    for (int i = t; i < 2048; i += 256) W2bs[i] = W2[512 + i];  // rows 32..159
    __syncthreads();

    int rl = t >> 5, c = t & 31;
    int r = blk * 8 + rl;

    float acc = 0.f;
    #pragma unroll 8
    for (int k = 0; k < 128; ++k) acc = fmaf(xs[rl * 128 + k], W1s[k * 32 + c], acc);
    ws[WS_T1 + r * 32 + c] = acc;

    if (c < 16) {
        float a2 = 0.f;
        #pragma unroll 8
        for (int k = 0; k < 128; ++k) a2 = fmaf(xs[rl * 128 + k], W2bs[k * 16 + c], a2);
        ws[WS_Y0 + r * 16 + c] = a2;
    }

    if (blk == 0 && t < 32) {
        float wa = 0.f, wb = 0.f;
        for (int h = 0; h < 32; ++h) {
            float w = Wc2[h];
            wa = fmaf(Wc1[t * 32 + h], w, wa);
            wb = fmaf(Wc1[(32 + t) * 32 + h], w, wb);
        }
        ws[WS_WA + t] = wa;
        ws[WS_WB + t] = wb;
        if (t == 0) {
            float cb = bc2[0];
            for (int h = 0; h < 32; ++h) cb = fmaf(bc1[h], Wc2[h], cb);
            ws[WS_CB] = cb;
        }
    }
}

// ---------------------------------------------------------------------------
// K2: partial2[ks][r][c] = sum_{j in ks-strip} adj[r,j] * t1[j,c]
// wave = 8 rows x 8 jgroups; 4 waves/block; 1024 blocks -> 4096 waves
// ---------------------------------------------------------------------------
__global__ __launch_bounds__(256, 4) void k2_mm(
    const float* __restrict__ A, const float* __restrict__ ws_in,
    float* __restrict__ ws_out)
{
    const float* t1 = ws_in + WS_T1;
    int t = threadIdx.x;
    int wv = t >> 6;
    int lane = t & 63;
    int w = blockIdx.x * 4 + wv;       // 0..4095
    int rg = w >> 4;                   // 0..255
    int ks = w & 15;                   // 0..15
    int jg = lane & 7;
    int rl = lane >> 3;
    int r = rg * 8 + rl;
    int jbase = ks * KS;

    const float* Arow = A + (size_t)r * N + jbase + jg * 4;

    float acc[32];
    #pragma unroll
    for (int c = 0; c < 32; ++c) acc[c] = 0.f;

    #pragma unroll
    for (int it = 0; it < KS / 32; ++it) {
        float4 a4 = *reinterpret_cast<const float4*>(Arow + it * 32);
        const float* trow = t1 + (jbase + it * 32 + jg * 4) * 32;
        #pragma unroll
        for (int jj = 0; jj < 4; ++jj) {
            float av = (jj == 0) ? a4.x : (jj == 1) ? a4.y : (jj == 2) ? a4.z : a4.w;
            const float* tr = trow + jj * 32;
            #pragma unroll
            for (int q8 = 0; q8 < 8; ++q8) {
                float4 tv = *reinterpret_cast<const float4*>(tr + q8 * 4);
                acc[q8 * 4 + 0] = fmaf(av, tv.x, acc[q8 * 4 + 0]);
                acc[q8 * 4 + 1] = fmaf(av, tv.y, acc[q8 * 4 + 1]);
                acc[q8 * 4 + 2] = fmaf(av, tv.z, acc[q8 * 4 + 2]);
                acc[q8 * 4 + 3] = fmaf(av, tv.w, acc[q8 * 4 + 3]);
            }
        }
    }

    // butterfly reduce across the 8 jgroups (lane bits 0..2)
    #pragma unroll
    for (int d = 1; d < 8; d <<= 1) {
        #pragma unroll
        for (int c = 0; c < 32; ++c) acc[c] += __shfl_xor(acc[c], d);
    }

    float4 o;
    o.x = acc[jg * 4 + 0]; o.y = acc[jg * 4 + 1];
    o.z = acc[jg * 4 + 2]; o.w = acc[jg * 4 + 3];
    *reinterpret_cast<float4*>(ws_out + WS_PART2 + ((size_t)(ks * N + r)) * 32 + jg * 4) = o;
}

// ---------------------------------------------------------------------------
// K2b: x = tanh(sum partials + b1); p,q row scalars; y = x@W2[:32] + y0
// block 256 = 8 rows x 32 lanes
// ---------------------------------------------------------------------------
__global__ __launch_bounds__(256) void k2b_post(
    const float* __restrict__ b1, const float* __restrict__ W2,
    float* __restrict__ ws)
{
    __shared__ float xs[8][32];
    int t = threadIdx.x;
    int rl = t >> 5, c = t & 31;
    int r = blockIdx.x * 8 + rl;

    const float* p2 = ws + WS_PART2;
    float s = b1[c];
    #pragma unroll
    for (int ks = 0; ks < NSTRIP; ++ks)
        s += p2[(size_t)(ks * N + r) * 32 + c];
    float x = tanhf(s);
    xs[rl][c] = x;
    __syncthreads();

    float pp = x * ws[WS_WA + c];
    float qq = x * ws[WS_WB + c];
    #pragma unroll
    for (int d = 1; d < 32; d <<= 1) {
        pp += __shfl_xor(pp, d);
        qq += __shfl_xor(qq, d);
    }
    if (c == 0) {
        ws[WS_PC + r] = pp + ws[WS_CB];
        ws[WS_Q + r] = qq;
    }

    if (c < 16) {
        float acc = ws[WS_Y0 + r * 16 + c];
        #pragma unroll 8
        for (int h = 0; h < 32; ++h) acc = fmaf(xs[rl][h], W2[h * 16 + c], acc);
        ws[WS_Y + r * 16 + c] = acc;
    }
}

// ---------------------------------------------------------------------------
// K3: partial3[ks][r][c16] = sum_{j in strip} adj[r,j]*score(pc[r]+q[j])*y[j,c16]
// ---------------------------------------------------------------------------
__global__ __launch_bounds__(256, 4) void k3_mm(
    const float* __restrict__ A, const float* __restrict__ ws_in,
    float* __restrict__ ws_out)
{
    const float* y = ws_in + WS_Y;
    const float* qv = ws_in + WS_Q;
    int t = threadIdx.x;
    int wv = t >> 6;
    int lane = t & 63;
    int w = blockIdx.x * 4 + wv;       // 0..4095
    int rg = w >> 4;
    int ks = w & 15;
    int jg = lane & 7;
    int rl = lane >> 3;
    int r = rg * 8 + rl;
    int jbase = ks * KS;

    float pcr = ws_in[WS_PC + r];
    const float* Arow = A + (size_t)r * N + jbase + jg * 4;

    float acc[16];
    #pragma unroll
    for (int c = 0; c < 16; ++c) acc[c] = 0.f;

    #pragma unroll
    for (int it = 0; it < KS / 32; ++it) {
        float4 a4 = *reinterpret_cast<const float4*>(Arow + it * 32);
        int j0 = jbase + it * 32 + jg * 4;
        float4 q4 = *reinterpret_cast<const float4*>(qv + j0);
        #pragma unroll
        for (int jj = 0; jj < 4; ++jj) {
            float av = (jj == 0) ? a4.x : (jj == 1) ? a4.y : (jj == 2) ? a4.z : a4.w;
            float qj = (jj == 0) ? q4.x : (jj == 1) ? q4.y : (jj == 2) ? q4.z : q4.w;
            float e = pcr + qj;
            float sc = (e > 0.f) ? 1.f : e;
            float coef = av * sc;
            const float* yr = y + (j0 + jj) * 16;
            #pragma unroll
            for (int q8 = 0; q8 < 4; ++q8) {
                float4 tv = *reinterpret_cast<const float4*>(yr + q8 * 4);
                acc[q8 * 4 + 0] = fmaf(coef, tv.x, acc[q8 * 4 + 0]);
                acc[q8 * 4 + 1] = fmaf(coef, tv.y, acc[q8 * 4 + 1]);
                acc[q8 * 4 + 2] = fmaf(coef, tv.z, acc[q8 * 4 + 2]);
                acc[q8 * 4 + 3] = fmaf(coef, tv.w, acc[q8 * 4 + 3]);
            }
        }
    }

    #pragma unroll
    for (int d = 1; d < 8; d <<= 1) {
        #pragma unroll
        for (int c = 0; c < 16; ++c) acc[c] += __shfl_xor(acc[c], d);
    }

    float2 o;
    o.x = acc[jg * 2 + 0];
    o.y = acc[jg * 2 + 1];
    *reinterpret_cast<float2*>(ws_out + WS_PART3 + ((size_t)(ks * N + r)) * 16 + jg * 2) = o;
}

// ---------------------------------------------------------------------------
// K3b: out[r] = log_softmax(sum partials + b2)
// block 256 = 16 rows x 16 lanes
// ---------------------------------------------------------------------------
__global__ __launch_bounds__(256) void k3b_lsm(
    const float* __restrict__ b2, const float* __restrict__ ws,
    float* __restrict__ out)
{
    int t = threadIdx.x;
    int rl = t >> 4, c = t & 15;
    int r = blockIdx.x * 16 + rl;

    const float* p3 = ws + WS_PART3;
    float o = b2[c];
    #pragma unroll
    for (int ks = 0; ks < NSTRIP; ++ks)
        o += p3[(size_t)(ks * N + r) * 16 + c];

    float m = o;
    #pragma unroll
    for (int d = 1; d < 16; d <<= 1) m = fmaxf(m, __shfl_xor(m, d));
    float ex = expf(o - m);
    float sm = ex;
    #pragma unroll
    for (int d = 1; d < 16; d <<= 1) sm += __shfl_xor(sm, d);

    out[r * 16 + c] = o - m - logf(sm);
}

// ---------------------------------------------------------------------------
extern "C" void kernel_launch(void* const* d_in, const int* in_sizes, int n_in,
                              void* d_out, int out_size, void* d_ws, size_t ws_size,
                              hipStream_t stream)
{
    const float* x_init = (const float*)d_in[0];
    // d_in[1] adj: unused by the reference
    const float* adj1   = (const float*)d_in[2];
    // d_in[3] fully_connected_graph: unused
    const float* W1  = (const float*)d_in[4];
    const float* b1  = (const float*)d_in[5];
    const float* W2  = (const float*)d_in[6];
    const float* b2  = (const float*)d_in[7];
    const float* Wc1 = (const float*)d_in[8];
    const float* bc1 = (const float*)d_in[9];
    const float* Wc2 = (const float*)d_in[10];
    const float* bc2 = (const float*)d_in[11];
    float* out = (float*)d_out;
    float* ws = (float*)d_ws;

    hipLaunchKernelGGL(k1_prep, dim3(256), dim3(256), 0, stream,
                       x_init, W1, W2, Wc1, bc1, Wc2, bc2, ws);
    hipLaunchKernelGGL(k2_mm, dim3(1024), dim3(256), 0, stream, adj1, ws, ws);
    hipLaunchKernelGGL(k2b_post, dim3(256), dim3(256), 0, stream, b1, W2, ws);
    hipLaunchKernelGGL(k3_mm, dim3(1024), dim3(256), 0, stream, adj1, ws, ws);
    hipLaunchKernelGGL(k3b_lsm, dim3(128), dim3(256), 0, stream, b2, ws, out);
}

// Round 6
// 121.536 us; speedup vs baseline: 1.6935x; 1.6705x over previous
//
#include <hip/hip_runtime.h>
#include <hip/hip_bf16.h>
#include <math.h>

// Problem constants
#define N 2048
#define NFEAT 128
#define NHID 32
#define NCLASS 16
#define NSTRIP 16          // K-split factor for the two N x N GEMMs
#define KS 128             // strip width = N / NSTRIP

// ws layout (float elements)
#define WS_T1    0                         // [2048][32]
#define WS_Y0    65536                     // [2048][16]
#define WS_WA    98304                     // [32]
#define WS_WB    98336                     // [32]
#define WS_CB    98368                     // [1] (+pad)
#define WS_PART2 98432                     // [16][2048][32]
#define WS_Y     1147008                   // [2048][16]
#define WS_PC    1179776                   // [2048]
#define WS_Q     1181824                   // [2048]
#define WS_PART3 1183872                   // [16][2048][16]
// total 1708160 floats = 6.83 MB

// ---------------------------------------------------------------------------
// K1: t1 = x_init @ W1 ; y0 = x_init @ W2[32:160] ; block0 computes wa,wb,cb
// ---------------------------------------------------------------------------
__global__ __launch_bounds__(256) void k1_prep(
    const float* __restrict__ x_init, const float* __restrict__ W1,
    const float* __restrict__ W2, const float* __restrict__ Wc1,
    const float* __restrict__ bc1, const float* __restrict__ Wc2,
    const float* __restrict__ bc2, float* __restrict__ ws)
{
    __shared__ float xs[8 * 128];
    __shared__ float W1s[128 * 32];
    __shared__ float W2bs[128 * 16];
    int t = threadIdx.x;
    int blk = blockIdx.x;

    // vectorized staging
    *reinterpret_cast<float4*>(&xs[4 * t]) =
        *reinterpret_cast<const float4*>(&x_init[blk * 1024 + 4 * t]);
    #pragma unroll
    for (int i = 0; i < 4; ++i) {
        int f = t + 256 * i;
        *reinterpret_cast<float4*>(&W1s[4 * f]) =
            *reinterpret_cast<const float4*>(&W1[4 * f]);
    }
    #pragma unroll
    for (int i = 0; i < 2; ++i) {
        int f = t + 256 * i;
        *reinterpret_cast<float4*>(&W2bs[4 * f]) =
            *reinterpret_cast<const float4*>(&W2[512 + 4 * f]);
    }
    __syncthreads();

    int rl = t >> 5, c = t & 31;
    int r = blk * 8 + rl;

    float acc = 0.f;
    #pragma unroll 8
    for (int k = 0; k < 128; ++k) acc = fmaf(xs[rl * 128 + k], W1s[k * 32 + c], acc);
    ws[WS_T1 + r * 32 + c] = acc;

    if (c < 16) {
        float a2 = 0.f;
        #pragma unroll 8
        for (int k = 0; k < 128; ++k) a2 = fmaf(xs[rl * 128 + k], W2bs[k * 16 + c], a2);
        ws[WS_Y0 + r * 16 + c] = a2;
    }

    if (blk == 0 && t < 32) {
        float wa = 0.f, wb = 0.f;
        for (int h = 0; h < 32; ++h) {
            float w = Wc2[h];
            wa = fmaf(Wc1[t * 32 + h], w, wa);
            wb = fmaf(Wc1[(32 + t) * 32 + h], w, wb);
        }
        ws[WS_WA + t] = wa;
        ws[WS_WB + t] = wb;
        if (t == 0) {
            float cb = bc2[0];
            for (int h = 0; h < 32; ++h) cb = fmaf(bc1[h], Wc2[h], cb);
            ws[WS_CB] = cb;
        }
    }
}

// ---------------------------------------------------------------------------
// K2: partial2[ks][r][c] = sum_{j in ks-strip} adj[r,j] * t1[j,c]
// LDS-tiled: block = 64 rows x 32 cols x K-strip 128; grid = 32 x 16 = 512
// thread (rg = t>>3 in 0..31, cg = t&7): rows {rg, rg+32}, cols cg*4..cg*4+3
// ---------------------------------------------------------------------------
__global__ __launch_bounds__(256, 2) void k2_mm(
    const float* __restrict__ A, const float* __restrict__ ws_in,
    float* __restrict__ ws_out)
{
    __shared__ float As[64][132];   // padded: row stride 132 breaks bank alias
    __shared__ float Bs[128][32];

    const float* t1 = ws_in + WS_T1;
    int t = threadIdx.x;
    int rt = blockIdx.x >> 4;      // 0..31 row tile
    int ks = blockIdx.x & 15;      // 0..15 K strip
    int row0 = rt * 64;
    int jbase = ks * KS;

    // stage A strip: 64 rows x 128 cols, coalesced float4
    #pragma unroll
    for (int i = 0; i < 8; ++i) {
        int f = t + 256 * i;               // 0..2047
        int r = f >> 5, c4 = f & 31;
        float4 v = *reinterpret_cast<const float4*>(
            &A[(size_t)(row0 + r) * N + jbase + 4 * c4]);
        *reinterpret_cast<float4*>(&As[r][4 * c4]) = v;
    }
    // stage B strip: t1 rows jbase..jbase+127
    #pragma unroll
    for (int i = 0; i < 4; ++i) {
        int f = t + 256 * i;               // 0..1023
        int r = f >> 3, c4 = f & 7;
        float4 v = *reinterpret_cast<const float4*>(&t1[(jbase + r) * 32 + 4 * c4]);
        *reinterpret_cast<float4*>(&Bs[r][4 * c4]) = v;
    }
    __syncthreads();

    int cg = t & 7;
    int rg = t >> 3;

    float acc0[4] = {0.f, 0.f, 0.f, 0.f};
    float acc1[4] = {0.f, 0.f, 0.f, 0.f};

    #pragma unroll
    for (int kq = 0; kq < 32; ++kq) {
        float4 a0 = *reinterpret_cast<const float4*>(&As[rg][4 * kq]);
        float4 a1 = *reinterpret_cast<const float4*>(&As[rg + 32][4 * kq]);
        float4 b0 = *reinterpret_cast<const float4*>(&Bs[4 * kq + 0][4 * cg]);
        float4 b1 = *reinterpret_cast<const float4*>(&Bs[4 * kq + 1][4 * cg]);
        float4 b2 = *reinterpret_cast<const float4*>(&Bs[4 * kq + 2][4 * cg]);
        float4 b3 = *reinterpret_cast<const float4*>(&Bs[4 * kq + 3][4 * cg]);

        acc0[0] = fmaf(a0.x, b0.x, acc0[0]); acc0[1] = fmaf(a0.x, b0.y, acc0[1]);
        acc0[2] = fmaf(a0.x, b0.z, acc0[2]); acc0[3] = fmaf(a0.x, b0.w, acc0[3]);
        acc1[0] = fmaf(a1.x, b0.x, acc1[0]); acc1[1] = fmaf(a1.x, b0.y, acc1[1]);
        acc1[2] = fmaf(a1.x, b0.z, acc1[2]); acc1[3] = fmaf(a1.x, b0.w, acc1[3]);

        acc0[0] = fmaf(a0.y, b1.x, acc0[0]); acc0[1] = fmaf(a0.y, b1.y, acc0[1]);
        acc0[2] = fmaf(a0.y, b1.z, acc0[2]); acc0[3] = fmaf(a0.y, b1.w, acc0[3]);
        acc1[0] = fmaf(a1.y, b1.x, acc1[0]); acc1[1] = fmaf(a1.y, b1.y, acc1[1]);
        acc1[2] = fmaf(a1.y, b1.z, acc1[2]); acc1[3] = fmaf(a1.y, b1.w, acc1[3]);

        acc0[0] = fmaf(a0.z, b2.x, acc0[0]); acc0[1] = fmaf(a0.z, b2.y, acc0[1]);
        acc0[2] = fmaf(a0.z, b2.z, acc0[2]); acc0[3] = fmaf(a0.z, b2.w, acc0[3]);
        acc1[0] = fmaf(a1.z, b2.x, acc1[0]); acc1[1] = fmaf(a1.z, b2.y, acc1[1]);
        acc1[2] = fmaf(a1.z, b2.z, acc1[2]); acc1[3] = fmaf(a1.z, b2.w, acc1[3]);

        acc0[0] = fmaf(a0.w, b3.x, acc0[0]); acc0[1] = fmaf(a0.w, b3.y, acc0[1]);
        acc0[2] = fmaf(a0.w, b3.z, acc0[2]); acc0[3] = fmaf(a0.w, b3.w, acc0[3]);
        acc1[0] = fmaf(a1.w, b3.x, acc1[0]); acc1[1] = fmaf(a1.w, b3.y, acc1[1]);
        acc1[2] = fmaf(a1.w, b3.z, acc1[2]); acc1[3] = fmaf(a1.w, b3.w, acc1[3]);
    }

    float* o0 = ws_out + WS_PART2 + ((size_t)(ks * N + row0 + rg)) * 32 + 4 * cg;
    float* o1 = ws_out + WS_PART2 + ((size_t)(ks * N + row0 + rg + 32)) * 32 + 4 * cg;
    *reinterpret_cast<float4*>(o0) = make_float4(acc0[0], acc0[1], acc0[2], acc0[3]);
    *reinterpret_cast<float4*>(o1) = make_float4(acc1[0], acc1[1], acc1[2], acc1[3]);
}

// ---------------------------------------------------------------------------
// K2b: x = tanh(sum partials + b1); p,q row scalars; y = x@W2[:32] + y0
// ---------------------------------------------------------------------------
__global__ __launch_bounds__(256) void k2b_post(
    const float* __restrict__ b1, const float* __restrict__ W2,
    float* __restrict__ ws)
{
    __shared__ float xs[8][32];
    int t = threadIdx.x;
    int rl = t >> 5, c = t & 31;
    int r = blockIdx.x * 8 + rl;

    const float* p2 = ws + WS_PART2;
    float s = b1[c];
    #pragma unroll
    for (int ks = 0; ks < NSTRIP; ++ks)
        s += p2[(size_t)(ks * N + r) * 32 + c];
    float x = tanhf(s);
    xs[rl][c] = x;
    __syncthreads();

    float pp = x * ws[WS_WA + c];
    float qq = x * ws[WS_WB + c];
    #pragma unroll
    for (int d = 1; d < 32; d <<= 1) {
        pp += __shfl_xor(pp, d);
        qq += __shfl_xor(qq, d);
    }
    if (c == 0) {
        ws[WS_PC + r] = pp + ws[WS_CB];
        ws[WS_Q + r] = qq;
    }

    if (c < 16) {
        float acc = ws[WS_Y0 + r * 16 + c];
        #pragma unroll 8
        for (int h = 0; h < 32; ++h) acc = fmaf(xs[rl][h], W2[h * 16 + c], acc);
        ws[WS_Y + r * 16 + c] = acc;
    }
}

// ---------------------------------------------------------------------------
// K3: partial3[ks][r][c] = sum_{j in strip} adj[r,j]*score(pc[r]+q[j])*y[j,c]
// LDS-tiled like k2: block = 64 rows x 16 cols x strip 128; grid 512
// thread (rg = t>>2 in 0..63, cg = t&3): 1 row, cols cg*4..cg*4+3
// ---------------------------------------------------------------------------
__global__ __launch_bounds__(256, 2) void k3_mm(
    const float* __restrict__ A, const float* __restrict__ ws_in,
    float* __restrict__ ws_out)
{
    __shared__ float As[64][132];
    __shared__ float Bs[128][16];

    const float* y = ws_in + WS_Y;
    const float* qv = ws_in + WS_Q;
    const float* pc = ws_in + WS_PC;
    int t = threadIdx.x;
    int rt = blockIdx.x >> 4;
    int ks = blockIdx.x & 15;
    int row0 = rt * 64;
    int jbase = ks * KS;

    // stage A strip with fused score transform
    #pragma unroll
    for (int i = 0; i < 8; ++i) {
        int f = t + 256 * i;
        int r = f >> 5, c4 = f & 31;
        int j0 = jbase + 4 * c4;
        float4 a = *reinterpret_cast<const float4*>(&A[(size_t)(row0 + r) * N + j0]);
        float4 q4 = *reinterpret_cast<const float4*>(&qv[j0]);
        float pcr = pc[row0 + r];
        float e0 = pcr + q4.x, e1 = pcr + q4.y, e2 = pcr + q4.z, e3 = pcr + q4.w;
        float4 cf;
        cf.x = a.x * ((e0 > 0.f) ? 1.f : e0);
        cf.y = a.y * ((e1 > 0.f) ? 1.f : e1);
        cf.z = a.z * ((e2 > 0.f) ? 1.f : e2);
        cf.w = a.w * ((e3 > 0.f) ? 1.f : e3);
        *reinterpret_cast<float4*>(&As[r][4 * c4]) = cf;
    }
    // stage y strip: 128 x 16
    #pragma unroll
    for (int i = 0; i < 2; ++i) {
        int f = t + 256 * i;               // 0..511
        int r = f >> 2, c4 = f & 3;
        float4 v = *reinterpret_cast<const float4*>(&y[(jbase + r) * 16 + 4 * c4]);
        *reinterpret_cast<float4*>(&Bs[r][4 * c4]) = v;
    }
    __syncthreads();

    int cg = t & 3;
    int rg = t >> 2;                       // 0..63

    float acc[4] = {0.f, 0.f, 0.f, 0.f};

    #pragma unroll
    for (int kq = 0; kq < 32; ++kq) {
        float4 a = *reinterpret_cast<const float4*>(&As[rg][4 * kq]);
        float4 b0 = *reinterpret_cast<const float4*>(&Bs[4 * kq + 0][4 * cg]);
        float4 b1 = *reinterpret_cast<const float4*>(&Bs[4 * kq + 1][4 * cg]);
        float4 b2 = *reinterpret_cast<const float4*>(&Bs[4 * kq + 2][4 * cg]);
        float4 b3 = *reinterpret_cast<const float4*>(&Bs[4 * kq + 3][4 * cg]);

        acc[0] = fmaf(a.x, b0.x, acc[0]); acc[1] = fmaf(a.x, b0.y, acc[1]);
        acc[2] = fmaf(a.x, b0.z, acc[2]); acc[3] = fmaf(a.x, b0.w, acc[3]);
        acc[0] = fmaf(a.y, b1.x, acc[0]); acc[1] = fmaf(a.y, b1.y, acc[1]);
        acc[2] = fmaf(a.y, b1.z, acc[2]); acc[3] = fmaf(a.y, b1.w, acc[3]);
        acc[0] = fmaf(a.z, b2.x, acc[0]); acc[1] = fmaf(a.z, b2.y, acc[1]);
        acc[2] = fmaf(a.z, b2.z, acc[2]); acc[3] = fmaf(a.z, b2.w, acc[3]);
        acc[0] = fmaf(a.w, b3.x, acc[0]); acc[1] = fmaf(a.w, b3.y, acc[1]);
        acc[2] = fmaf(a.w, b3.z, acc[2]); acc[3] = fmaf(a.w, b3.w, acc[3]);
    }

    float* o = ws_out + WS_PART3 + ((size_t)(ks * N + row0 + rg)) * 16 + 4 * cg;
    *reinterpret_cast<float4*>(o) = make_float4(acc[0], acc[1], acc[2], acc[3]);
}

// ---------------------------------------------------------------------------
// K3b: out[r] = log_softmax(sum partials + b2)
// ---------------------------------------------------------------------------
__global__ __launch_bounds__(256) void k3b_lsm(
    const float* __restrict__ b2, const float* __restrict__ ws,
    float* __restrict__ out)
{
    int t = threadIdx.x;
    int rl = t >> 4, c = t & 15;
    int r = blockIdx.x * 16 + rl;

    const float* p3 = ws + WS_PART3;
    float o = b2[c];
    #pragma unroll
    for (int ks = 0; ks < NSTRIP; ++ks)
        o += p3[(size_t)(ks * N + r) * 16 + c];

    float m = o;
    #pragma unroll
    for (int d = 1; d < 16; d <<= 1) m = fmaxf(m, __shfl_xor(m, d));
    float ex = expf(o - m);
    float sm = ex;
    #pragma unroll
    for (int d = 1; d < 16; d <<= 1) sm += __shfl_xor(sm, d);

    out[r * 16 + c] = o - m - logf(sm);
}

// ---------------------------------------------------------------------------
extern "C" void kernel_launch(void* const* d_in, const int* in_sizes, int n_in,
                              void* d_out, int out_size, void* d_ws, size_t ws_size,
                              hipStream_t stream)
{
    const float* x_init = (const float*)d_in[0];
    // d_in[1] adj: unused by the reference
    const float* adj1   = (const float*)d_in[2];
    // d_in[3] fully_connected_graph: unused
    const float* W1  = (const float*)d_in[4];
    const float* b1  = (const float*)d_in[5];
    const float* W2  = (const float*)d_in[6];
    const float* b2  = (const float*)d_in[7];
    const float* Wc1 = (const float*)d_in[8];
    const float* bc1 = (const float*)d_in[9];
    const float* Wc2 = (const float*)d_in[10];
    const float* bc2 = (const float*)d_in[11];
    float* out = (float*)d_out;
    float* ws = (float*)d_ws;

    hipLaunchKernelGGL(k1_prep, dim3(256), dim3(256), 0, stream,
                       x_init, W1, W2, Wc1, bc1, Wc2, bc2, ws);
    hipLaunchKernelGGL(k2_mm, dim3(512), dim3(256), 0, stream, adj1, ws, ws);
    hipLaunchKernelGGL(k2b_post, dim3(256), dim3(256), 0, stream, b1, W2, ws);
    hipLaunchKernelGGL(k3_mm, dim3(512), dim3(256), 0, stream, adj1, ws, ws);
    hipLaunchKernelGGL(k3b_lsm, dim3(128), dim3(256), 0, stream, b2, ws, out);
}